// Round 8
// baseline (25160.597 us; speedup 1.0000x reference)
//
#include <hip/hip_runtime.h>
#include <hip/hip_bf16.h>
#include <math.h>

#define IDIM 128
#define HDIM 512
#define SDIM 64
#define BATCH 128
#define MAXT 259
#define G4 2048
#define KTOT 704   // 128 (x) + 64 (rt) + 512 (h)
#define ROUT 194   // 64 + 128 + 2
#define AFRAG_SH 73728   // 8 mt * 18 ks * 64 lanes * 8 e (shorts) per buffer
#define NBLK 256

typedef __hip_bfloat16 bf16;
typedef __attribute__((ext_vector_type(8))) short short8;
typedef __attribute__((ext_vector_type(4))) float floatx4;

__device__ __forceinline__ float sigmoidf_(float v) { return 1.f / (1.f + expf(-v)); }
__device__ __forceinline__ float b2f(bf16 v) { return __bfloat162float(v); }
__device__ __forceinline__ float load_in(const void* p, size_t i, int isf32) {
    return isf32 ? ((const float*)p)[i] : b2f(((const bf16*)p)[i]);
}
__device__ __forceinline__ unsigned short f2bfbits(float v) {
    unsigned u = __builtin_bit_cast(unsigned, v);
    unsigned r = (u + 0x7FFFu + ((u >> 16) & 1u)) >> 16;
    return (unsigned short)r;
}
__device__ __forceinline__ float bfbits2f(unsigned short b) {
    return __builtin_bit_cast(float, (unsigned)b << 16);
}

// Flag-array grid barrier. 256 co-resident blocks. Arrival: parallel relaxed
// stores (no RMW serialization). Root = block NBLK-1 (gates-only -> arrives
// early) aggregates 256 flags with 256 threads, publishes gen. Exactly ONE
// threadfence (L2 wb/inv) per block on each side — not per poll iteration.
__device__ __forceinline__ void grid_barrier(unsigned* flags, unsigned* gen,
                                             unsigned target) {
    __syncthreads();
    __threadfence();   // release: publish this block's stores
    if (threadIdx.x == 0)
        __hip_atomic_store(&flags[blockIdx.x * 16], target,
                           __ATOMIC_RELAXED, __HIP_MEMORY_SCOPE_AGENT);
    if (blockIdx.x == NBLK - 1) {
        while (__hip_atomic_load(&flags[threadIdx.x * 16], __ATOMIC_RELAXED,
                                 __HIP_MEMORY_SCOPE_AGENT) < target)
            __builtin_amdgcn_s_sleep(1);
        __syncthreads();
        if (threadIdx.x == 0) {
            __threadfence();
            __hip_atomic_store(gen, target, __ATOMIC_RELAXED,
                               __HIP_MEMORY_SCOPE_AGENT);
        }
    } else {
        if (threadIdx.x == 0) {
            while (__hip_atomic_load(gen, __ATOMIC_RELAXED,
                                     __HIP_MEMORY_SCOPE_AGENT) < target)
                __builtin_amdgcn_s_sleep(1);
        }
    }
    __syncthreads();
    __threadfence();   // acquire: invalidate stale L1/L2 before consuming
}

// dtype detect (defensive): f32 data has random low halves -> bf16-exp >= 0x8F
__global__ void detect_kernel(const unsigned short* __restrict__ w, int* __restrict__ flag) {
    if (threadIdx.x == 0) {
        int isf32 = 0;
        for (int i = 0; i < 256; i++) {
            int e = (w[i] >> 7) & 0xFF;
            if (e >= 0x8F) isf32 = 1;
        }
        *flag = isf32;
    }
}

// Gate-interleaved combined weights in B-fragment layout (hi/lo bf16 split).
__global__ void prep_kernel(const void* __restrict__ Wih, const void* __restrict__ bih,
                            const void* __restrict__ Whh, const void* __restrict__ bhh,
                            unsigned short* __restrict__ WfH, unsigned short* __restrict__ WfL,
                            float* __restrict__ bc, const int* __restrict__ flag) {
    int isf32 = *flag;
    int jp = blockIdx.x;
    int u = jp >> 2, gate = jp & 3;
    int src = gate * HDIM + u;
    int jt = jp >> 4, jn = jp & 15;
    for (int k = threadIdx.x; k < KTOT; k += blockDim.x) {
        float v = (k < 192) ? load_in(Wih, (size_t)src * 192 + k, isf32)
                            : load_in(Whh, (size_t)src * HDIM + (k - 192), isf32);
        unsigned short hi = f2bfbits(v);
        unsigned short lo = f2bfbits(v - bfbits2f(hi));
        int ks = k >> 5, q = (k & 31) >> 3, e = k & 7;
        size_t d = (((size_t)jt * 22 + ks) * 64 + (q * 16 + jn)) * 8 + e;
        WfH[d] = hi;
        WfL[d] = lo;
    }
    if (threadIdx.x == 0)
        bc[jp] = load_in(bih, src, isf32) + load_in(bhh, src, isf32);
}

// Wr -> row-major bf16 hi/lo (208 rows, rows >=194 zero) + brf f32 (padded).
__global__ void wr_prep_kernel(const void* __restrict__ Wr, const void* __restrict__ br,
                               unsigned short* __restrict__ WrBh, unsigned short* __restrict__ WrBl,
                               float* __restrict__ brf, const int* __restrict__ flag) {
    int isf32 = *flag;
    int j = blockIdx.x;
    for (int k = threadIdx.x; k < HDIM; k += blockDim.x) {
        float v = (j < ROUT) ? load_in(Wr, (size_t)j * HDIM + k, isf32) : 0.f;
        unsigned short hi = f2bfbits(v);
        WrBh[(size_t)j * HDIM + k] = hi;
        WrBl[(size_t)j * HDIM + k] = f2bfbits(v - bfbits2f(hi));
    }
    if (threadIdx.x == 0) brf[j] = (j < ROUT) ? load_in(br, j, isf32) : 0.f;
}

// Pre-convert x[t] (t=0..128) into A-fragment layout (hi only).
__global__ void x_prep_kernel(const void* __restrict__ x, unsigned short* __restrict__ xF,
                              const int* __restrict__ flag) {
    int isf32 = *flag;
    int t = blockIdx.x;
    for (int idx = threadIdx.x; idx < BATCH * IDIM; idx += blockDim.x) {
        int m = idx >> 7, k = idx & 127;
        float v = load_in(x, (size_t)t * BATCH * IDIM + idx, isf32);
        int mt = m >> 4, ks = k >> 5, q = (k & 31) >> 3, e = k & 7;
        size_t d = (size_t)t * 16384 + (((mt * 4 + ks) * 64) + q * 16 + (m & 15)) * 8 + e;
        xF[d] = f2bfbits(v);
    }
}

// ---------------- persistent kernel, flag barrier, 256 blocks ----------------
// blk = ms*32+ns: gates tile rows 16ms..+15, j'-cols 64ns..+63 (wave wv owns
// n-tile ns*4+wv). Blocks 0..127 additionally run P2 for batch row blk.
// Readout is computed as per-block partials (local h x LDS Wr-slice) in P1;
// row-blocks only sum 32 partials in P2. V lives in row-block LDS.
__global__ __launch_bounds__(256) void persist_kernel(
        const unsigned short* __restrict__ xF,
        const unsigned short* __restrict__ WfH, const unsigned short* __restrict__ WfL,
        const float* __restrict__ bc,
        const unsigned short* __restrict__ WrBh, const unsigned short* __restrict__ WrBl,
        const float* __restrict__ brf,
        unsigned short* __restrict__ AfH, unsigned short* __restrict__ AfL,
        float* __restrict__ part, void* __restrict__ dout,
        const int* __restrict__ flag, unsigned* __restrict__ bar) {
    __shared__ __align__(16) unsigned short wrsl[208 * 16];   // Wr hi slice (cols of ns)
    __shared__ __align__(16) unsigned short wrslL[208 * 16];  // Wr lo slice
    __shared__ __align__(16) unsigned short Vl[MAXT * SDIM];  // V row (bf16), row-blocks
    __shared__ __align__(16) float scr[4][16][20];
    __shared__ __align__(16) float hl[16][17];
    __shared__ __align__(16) float outs[208];
    __shared__ __align__(16) float sL[324];
    __shared__ __align__(16) float aL[324];
    __shared__ __align__(16) float red[4][64];
    __shared__ __align__(16) float brS[208];
    __shared__ __align__(16) float bcS[64];

    const int tid = threadIdx.x, lane = tid & 63, wv = tid >> 6;
    const int blk = blockIdx.x, ms = blk >> 5, ns = blk & 31;
    const int isf32 = *flag;
    unsigned* flags = bar;
    unsigned* gen = bar + 256 * 16;

    for (int i = tid; i < 208 * 16; i += 256) {
        int j = i >> 4, ui = i & 15;
        wrsl[i]  = WrBh[(size_t)j * HDIM + ns * 16 + ui];
        wrslL[i] = WrBl[(size_t)j * HDIM + ns * 16 + ui];
    }
    for (int i = tid; i < 208; i += 256) brS[i] = brf[i];
    if (tid < 64) bcS[tid] = bc[ns * 64 + tid];
    for (int i = tid; i < 324; i += 256) { sL[i] = 0.f; aL[i] = 0.f; }
    float cc = 0.f;
    __syncthreads();

    const short8* WH = (const short8*)WfH;
    const short8* WL = (const short8*)WfL;
    const int nt = ns * 4 + wv;

    for (int t = 0; t < MAXT; t++) {
        const int cur = t & 1, nxt = cur ^ 1;
        const short8* AhC = (const short8*)(AfH + (size_t)cur * AFRAG_SH);
        const short8* AlC = (const short8*)(AfL + (size_t)cur * AFRAG_SH);
        unsigned short* AfHn = AfH + (size_t)nxt * AFRAG_SH;
        unsigned short* AfLn = AfL + (size_t)nxt * AFRAG_SH;
        const int use_x = (t < 129);

        // ---- P1: gates MFMA (one 16x16 acc per wave) ----
        floatx4 acc = {0.f, 0.f, 0.f, 0.f};
        const short8* wb  = WH + (size_t)nt * 22 * 64;
        const short8* wbl = WL + (size_t)nt * 22 * 64;
        if (use_x) {
            const short8* xb = (const short8*)xF + (size_t)t * 2048;
            #pragma unroll
            for (int ks = 0; ks < 4; ks++) {
                short8 a = xb[(ms * 4 + ks) * 64 + lane];
                short8 bh = wb[ks * 64 + lane];
                acc = __builtin_amdgcn_mfma_f32_16x16x32_bf16(a, bh, acc, 0, 0, 0);
                if (isf32)
                    acc = __builtin_amdgcn_mfma_f32_16x16x32_bf16(a, wbl[ks * 64 + lane], acc, 0, 0, 0);
            }
        }
        #pragma unroll 6
        for (int ksi = 0; ksi < 18; ksi++) {
            int ks = 4 + ksi;
            short8 ah = AhC[(ms * 18 + ksi) * 64 + lane];
            short8 al = AlC[(ms * 18 + ksi) * 64 + lane];
            short8 bh = wb[ks * 64 + lane];
            acc = __builtin_amdgcn_mfma_f32_16x16x32_bf16(ah, bh, acc, 0, 0, 0);
            acc = __builtin_amdgcn_mfma_f32_16x16x32_bf16(al, bh, acc, 0, 0, 0);
            if (isf32)
                acc = __builtin_amdgcn_mfma_f32_16x16x32_bf16(ah, wbl[ks * 64 + lane], acc, 0, 0, 0);
        }
        {
            int n = lane & 15, m0 = (lane >> 4) * 4;
            #pragma unroll
            for (int r = 0; r < 4; r++) scr[wv][m0 + r][n] = acc[r];
        }
        __syncthreads();
        // cell epilogue: thread = (row r, local-u ul); c in one VGPR
        {
            int r = tid >> 4, ul = tid & 15;
            float4 g = *(const float4*)&scr[ul >> 2][r][(ul & 3) * 4];
            float4 bb = *(const float4*)&bcS[ul * 4];
            float c2 = sigmoidf_(g.y + bb.y) * cc + sigmoidf_(g.x + bb.x) * tanhf(g.z + bb.z);
            float h2 = sigmoidf_(g.w + bb.w) * tanhf(c2);
            cc = c2;
            hl[r][ul] = h2;
            int u_g = ns * 16 + ul;
            unsigned short hb = f2bfbits(h2);
            unsigned short lb = f2bfbits(h2 - bfbits2f(hb));
            int ksi2 = 2 + (u_g >> 5), q = (u_g & 31) >> 3, e = u_g & 7;
            size_t fi = (((size_t)ms * 18 + ksi2) * 64 + q * 16 + r) * 8 + e;
            AfHn[fi] = hb;
            AfLn[fi] = lb;
        }
        __syncthreads();
        // readout partials: rows of this block x Wr-slice (16 cols of ns)
        {
            int jset = tid >> 4, r2 = tid & 15;
            int row = ms * 16 + r2;
            #pragma unroll
            for (int i = 0; i < 13; i++) {
                int j = jset * 13 + i;
                float p = 0.f;
                #pragma unroll
                for (int k = 0; k < 16; k++) p += bfbits2f(wrsl[j * 16 + k]) * hl[r2][k];
                if (isf32) {
                    #pragma unroll
                    for (int k = 0; k < 16; k++) p += bfbits2f(wrslL[j * 16 + k]) * hl[r2][k];
                }
                part[((size_t)row * 208 + j) * 32 + ns] = p;
            }
        }
        grid_barrier(flags, gen, 2 * t + 1);

        // ---- P2: row-blocks only ----
        if (blk < 128) {
            const int brow = blk;
            if (tid < 208) {
                const float4* pp = (const float4*)(part + ((size_t)brow * 208 + tid) * 32);
                float s4 = 0.f;
                #pragma unroll
                for (int i = 0; i < 8; i++) { float4 v = pp[i]; s4 += v.x + v.y + v.z + v.w; }
                outs[tid] = s4 + brS[tid];
            }
            __syncthreads();
            if (wv == 0) {
                float uval = sigmoidf_(outs[192]);
                float dval = sigmoidf_(outs[193]);
                Vl[t * SDIM + lane] = f2bfbits(outs[lane]);
                int ebase = lane * 5;
                float sv[5], suf[5];
                #pragma unroll
                for (int j = 0; j < 5; j++) {
                    int e = ebase + j;
                    sv[j] = (e < MAXT) ? sL[e] : 0.f;
                }
                suf[4] = sv[4];
                #pragma unroll
                for (int j = 3; j >= 0; j--) suf[j] = sv[j] + suf[j + 1];
                float ltot = suf[0];
                float accs = ltot;
                #pragma unroll
                for (int off = 1; off < 64; off <<= 1) {
                    float y = __shfl_down(accs, off, 64);
                    if (lane + off < 64) accs += y;
                }
                float after_lane = accs - ltot;
                #pragma unroll
                for (int j = 0; j < 5; j++) {
                    int e = ebase + j;
                    if (e < MAXT) {
                        float prod = after_lane + (suf[j] - sv[j]);
                        float sp = (e == t) ? dval
                                            : fmaxf(0.f, sv[j] - fmaxf(0.f, uval - prod));
                        float inner = fmaxf(0.f, 1.f - prod - sp);
                        sL[e] = sp;
                        aL[e] = fminf(sp, inner);
                    }
                }
            }
            __syncthreads();
            {
                float racc = 0.f;
                for (int i2 = wv; i2 <= t; i2 += 4)
                    racc += aL[i2] * bfbits2f(Vl[i2 * SDIM + lane]);
                red[wv][lane] = racc;
            }
            __syncthreads();
            if (wv == 0) {
                float rtv = red[0][lane] + red[1][lane] + red[2][lane] + red[3][lane];
                unsigned short hb = f2bfbits(rtv);
                unsigned short lb = f2bfbits(rtv - bfbits2f(hb));
                int mtB = brow >> 4;
                size_t fi = (((size_t)mtB * 18 + (lane >> 5)) * 64
                             + ((lane & 31) >> 3) * 16 + (brow & 15)) * 8 + (lane & 7);
                AfHn[fi] = hb;
                AfLn[fi] = lb;
            } else if (wv == 1 && t >= 129) {
                float a = outs[64 + lane];
                float bvv = outs[128 + lane];
                float m = fmaxf(a, bvv);
                #pragma unroll
                for (int off = 32; off; off >>= 1) m = fmaxf(m, __shfl_xor(m, off, 64));
                float e = expf(a - m) + expf(bvv - m);
                #pragma unroll
                for (int off = 32; off; off >>= 1) e += __shfl_xor(e, off, 64);
                float ls = logf(e) + m;
                size_t base = ((size_t)(t - 129) * BATCH + brow) * IDIM;
                if (isf32) {
                    ((float*)dout)[base + lane] = a - ls;
                    ((float*)dout)[base + lane + 64] = bvv - ls;
                } else {
                    ((bf16*)dout)[base + lane] = __float2bfloat16(a - ls);
                    ((bf16*)dout)[base + lane + 64] = __float2bfloat16(bvv - ls);
                }
            }
        }
        grid_barrier(flags, gen, 2 * t + 2);
    }
}

extern "C" void kernel_launch(void* const* d_in, const int* in_sizes, int n_in,
                              void* d_out, int out_size, void* d_ws, size_t ws_size,
                              hipStream_t stream) {
    const void* x   = d_in[0];
    const void* Wih = d_in[1];
    const void* bih = d_in[2];
    const void* Whh = d_in[3];
    const void* bhh = d_in[4];
    const void* Wr  = d_in[5];
    const void* br  = d_in[6];

    char* base = (char*)d_ws;
    size_t off = 0;
    int* flag = (int*)base;                                   off += 64;
    unsigned* bar = (unsigned*)(base + off);                  off += 256 * 64 + 64;  // flags + gen
    unsigned short* WfH  = (unsigned short*)(base + off);     off += (size_t)G4 * KTOT * 2;
    unsigned short* WfL  = (unsigned short*)(base + off);     off += (size_t)G4 * KTOT * 2;
    unsigned short* WrBh = (unsigned short*)(base + off);     off += (size_t)208 * HDIM * 2;
    unsigned short* WrBl = (unsigned short*)(base + off);     off += (size_t)208 * HDIM * 2;
    float* bc   = (float*)(base + off);                       off += G4 * 4;
    float* brf  = (float*)(base + off);                       off += 1024;
    unsigned short* xF = (unsigned short*)(base + off);       off += (size_t)129 * 16384 * 2;
    unsigned short* AfH = (unsigned short*)(base + off);      size_t afh_off = off;
                                                              off += (size_t)2 * AFRAG_SH * 2;
    unsigned short* AfL = (unsigned short*)(base + off);      off += (size_t)2 * AFRAG_SH * 2;
    float* part = (float*)(base + off);                       off += (size_t)BATCH * 208 * 32 * 4;
    // total ~13.8 MB

    hipMemsetAsync(base + 64, 0, 256 * 64 + 64, stream);                  // barrier flags + gen
    hipMemsetAsync(base + afh_off, 0, (size_t)4 * AFRAG_SH * 2, stream);  // Af hi/lo, both buffers

    detect_kernel<<<1, 64, 0, stream>>>((const unsigned short*)Wih, flag);
    prep_kernel<<<G4, 256, 0, stream>>>(Wih, bih, Whh, bhh, WfH, WfL, bc, flag);
    wr_prep_kernel<<<208, 256, 0, stream>>>(Wr, br, WrBh, WrBl, brf, flag);
    x_prep_kernel<<<129, 256, 0, stream>>>(x, xF, flag);

    persist_kernel<<<NBLK, 256, 0, stream>>>(xF, WfH, WfL, bc, WrBh, WrBl, brf,
                                             AfH, AfL, part, d_out, flag, bar);

    (void)in_sizes; (void)n_in; (void)out_size; (void)ws_size;
}

// Round 9
// 6696.697 us; speedup vs baseline: 3.7572x; 3.7572x over previous
//
#include <hip/hip_runtime.h>
#include <hip/hip_bf16.h>
#include <math.h>

#define IDIM 128
#define HDIM 512
#define SDIM 64
#define BATCH 128
#define MAXT 259
#define G4 2048
#define KTOT 704    // 128 (x) + 64 (rt) + 512 (h)
#define ROUT 194    // 64 + 128 + 2
#define AFRAG_U 73728   // 8 mt * 18 ks * 64 lanes * 8 e (uints, hi|lo packed) per buffer
#define NBLK 256

typedef __hip_bfloat16 bf16;
typedef __attribute__((ext_vector_type(8))) short short8;
typedef __attribute__((ext_vector_type(4))) float floatx4;

__device__ __forceinline__ float sigmoidf_(float v) { return 1.f / (1.f + expf(-v)); }
__device__ __forceinline__ float b2f(bf16 v) { return __bfloat162float(v); }
__device__ __forceinline__ float load_in(const void* p, size_t i, int isf32) {
    return isf32 ? ((const float*)p)[i] : b2f(((const bf16*)p)[i]);
}
__device__ __forceinline__ unsigned short f2bfbits(float v) {
    unsigned u = __builtin_bit_cast(unsigned, v);
    unsigned r = (u + 0x7FFFu + ((u >> 16) & 1u)) >> 16;
    return (unsigned short)r;
}
__device__ __forceinline__ float bfbits2f(unsigned short b) {
    return __builtin_bit_cast(float, (unsigned)b << 16);
}
__device__ __forceinline__ unsigned aload(const unsigned* p) {
    return __hip_atomic_load(p, __ATOMIC_RELAXED, __HIP_MEMORY_SCOPE_AGENT);
}
__device__ __forceinline__ unsigned long long aload64(const unsigned long long* p) {
    return __hip_atomic_load(p, __ATOMIC_RELAXED, __HIP_MEMORY_SCOPE_AGENT);
}
__device__ __forceinline__ void astore(unsigned* p, unsigned v) {
    __hip_atomic_store(p, v, __ATOMIC_RELAXED, __HIP_MEMORY_SCOPE_AGENT);
}

// Fence-free grid barrier: relaxed-atomic flag array (one 64B-spaced slot per
// block), per-wave vmcnt drain orders prior data stores before the flag store.
// NO __threadfence -> no L2 writeback/invalidate (the R7/R8 killer).
// 256 blocks <= 256 CUs -> co-residency guaranteed.
__device__ __forceinline__ void flag_barrier(unsigned* flags, unsigned epoch) {
    asm volatile("s_waitcnt vmcnt(0)" ::: "memory");
    __syncthreads();
    if (threadIdx.x == 0)
        astore(&flags[blockIdx.x * 16], epoch);
    while (aload(&flags[threadIdx.x * 16]) < epoch)
        __builtin_amdgcn_s_sleep(2);
    __atomic_signal_fence(__ATOMIC_SEQ_CST);
    __syncthreads();
}

// dtype detect (defensive): f32 data has random low halves -> bf16-exp >= 0x8F
__global__ void detect_kernel(const unsigned short* __restrict__ w, int* __restrict__ flag) {
    if (threadIdx.x == 0) {
        int isf32 = 0;
        for (int i = 0; i < 256; i++) {
            int e = (w[i] >> 7) & 0xFF;
            if (e >= 0x8F) isf32 = 1;
        }
        *flag = isf32;
    }
}

// Gate-interleaved combined weights in B-fragment layout (hi/lo bf16 split).
__global__ void prep_kernel(const void* __restrict__ Wih, const void* __restrict__ bih,
                            const void* __restrict__ Whh, const void* __restrict__ bhh,
                            unsigned short* __restrict__ WfH, unsigned short* __restrict__ WfL,
                            float* __restrict__ bc, const int* __restrict__ flag) {
    int isf32 = *flag;
    int jp = blockIdx.x;
    int u = jp >> 2, gate = jp & 3;
    int src = gate * HDIM + u;
    int jt = jp >> 4, jn = jp & 15;
    for (int k = threadIdx.x; k < KTOT; k += blockDim.x) {
        float v = (k < 192) ? load_in(Wih, (size_t)src * 192 + k, isf32)
                            : load_in(Whh, (size_t)src * HDIM + (k - 192), isf32);
        unsigned short hi = f2bfbits(v);
        unsigned short lo = f2bfbits(v - bfbits2f(hi));
        int ks = k >> 5, q = (k & 31) >> 3, e = k & 7;
        size_t d = (((size_t)jt * 22 + ks) * 64 + (q * 16 + jn)) * 8 + e;
        WfH[d] = hi;
        WfL[d] = lo;
    }
    if (threadIdx.x == 0)
        bc[jp] = load_in(bih, src, isf32) + load_in(bhh, src, isf32);
}

// Wr -> row-major bf16 hi/lo (208 rows, rows >=194 zero) + brf f32 (padded).
__global__ void wr_prep_kernel(const void* __restrict__ Wr, const void* __restrict__ br,
                               unsigned short* __restrict__ WrBh, unsigned short* __restrict__ WrBl,
                               float* __restrict__ brf, const int* __restrict__ flag) {
    int isf32 = *flag;
    int j = blockIdx.x;
    for (int k = threadIdx.x; k < HDIM; k += blockDim.x) {
        float v = (j < ROUT) ? load_in(Wr, (size_t)j * HDIM + k, isf32) : 0.f;
        unsigned short hi = f2bfbits(v);
        WrBh[(size_t)j * HDIM + k] = hi;
        WrBl[(size_t)j * HDIM + k] = f2bfbits(v - bfbits2f(hi));
    }
    if (threadIdx.x == 0) brf[j] = (j < ROUT) ? load_in(br, j, isf32) : 0.f;
}

// ---------------- persistent kernel, fence-free flag barrier ----------------
// 256 blocks x 256 threads. blk = ms*32+ns: gates tile rows 16ms..+15,
// j'-cols 64ns..+63 (wave wv owns n-tile ns*4+wv). Blocks 0..127 additionally
// run P2 for batch row blk. Cross-block data (AfP frags, part) is accessed
// ONLY via relaxed agent atomics (L3-coherent, no cache maintenance).
__global__ __launch_bounds__(256) void persist_kernel(
        const void* __restrict__ x,
        const unsigned short* __restrict__ WfH, const unsigned short* __restrict__ WfL,
        const float* __restrict__ bc,
        const unsigned short* __restrict__ WrBh, const unsigned short* __restrict__ WrBl,
        const float* __restrict__ brf,
        unsigned* __restrict__ AfP,          // 2 x AFRAG_U uints (hi | lo<<16)
        float* __restrict__ part,            // [128 rows][32 ns][208 j]
        unsigned short* __restrict__ Vg,     // [128][259][64] bf16, block-private
        void* __restrict__ dout, const int* __restrict__ flag,
        unsigned* __restrict__ flags) {
    __shared__ __align__(16) short Ahs[18 * 64 * 8];          // staged A hi (rt|h)
    __shared__ __align__(16) short Als[18 * 64 * 8];          // staged A lo
    __shared__ __align__(16) unsigned short wrsl[208 * 16];   // Wr hi slice (16 cols of ns)
    __shared__ __align__(16) unsigned short wrslL[208 * 16];  // Wr lo slice
    __shared__ __align__(16) float scr[4][16][20];
    __shared__ __align__(16) float hl[16][17];
    __shared__ __align__(16) float outs[208];
    __shared__ __align__(16) float sL[324];
    __shared__ __align__(16) float aL[324];
    __shared__ __align__(16) float red[4][64];
    __shared__ __align__(16) float brS[208];
    __shared__ __align__(16) float bcS[64];

    const int tid = threadIdx.x, lane = tid & 63, wv = tid >> 6;
    const int blk = blockIdx.x, ms = blk >> 5, ns = blk & 31;
    const int isf32 = *flag;

    for (int i = tid; i < 208 * 16; i += 256) {
        int j = i >> 4, ui = i & 15;
        wrsl[i]  = WrBh[(size_t)j * HDIM + ns * 16 + ui];
        wrslL[i] = WrBl[(size_t)j * HDIM + ns * 16 + ui];
    }
    for (int i = tid; i < 208; i += 256) brS[i] = brf[i];
    if (tid < 64) bcS[tid] = bc[ns * 64 + tid];
    for (int i = tid; i < 324; i += 256) { sL[i] = 0.f; aL[i] = 0.f; }
    float cc = 0.f;
    __syncthreads();

    const short8* WH = (const short8*)WfH;
    const short8* WL = (const short8*)WfL;
    const int nt = ns * 4 + wv;
    unsigned short* Vrow = Vg + (size_t)blk * MAXT * SDIM;    // blocks 0..127 only

    for (int t = 0; t < MAXT; t++) {
        const int cur = t & 1, nxt = cur ^ 1;
        const unsigned* AfPc = AfP + (size_t)cur * AFRAG_U;
        unsigned* AfPn = AfP + (size_t)nxt * AFRAG_U;
        const int use_x = (t < 129);

        // ---- P0: stage A-frags (rt|h, 18 ks) packed->LDS via relaxed atomics ----
        for (int i = tid; i < 18 * 64; i += 256) {
            int ksi = i >> 6, l = i & 63;
            const unsigned long long* ap =
                (const unsigned long long*)AfPc + ((size_t)(ms * 18 + ksi) * 64 + l) * 4;
            short8 ah, al8;
            #pragma unroll
            for (int j = 0; j < 4; j++) {
                unsigned long long q = aload64(ap + j);
                unsigned u0 = (unsigned)q, u1 = (unsigned)(q >> 32);
                ah[2 * j]     = (short)(u0 & 0xffffu);
                al8[2 * j]    = (short)(u0 >> 16);
                ah[2 * j + 1] = (short)(u1 & 0xffffu);
                al8[2 * j + 1] = (short)(u1 >> 16);
            }
            *(short8*)&Ahs[i * 8] = ah;
            *(short8*)&Als[i * 8] = al8;
        }
        __syncthreads();

        // ---- P1: gates MFMA (one 16x16 acc per wave) ----
        floatx4 acc = {0.f, 0.f, 0.f, 0.f};
        const short8* wb  = WH + (size_t)nt * 22 * 64;
        const short8* wbl = WL + (size_t)nt * 22 * 64;
        if (use_x) {
            // x fragment read directly from row-major input: lane (q*16+m) gets
            // x[t*128 + ms*16 + m][ks*32 + q*8 .. +7] (contiguous 8 elems)
            int m = lane & 15, q = lane >> 4;
            size_t xrow = ((size_t)t * BATCH + ms * 16 + m) * IDIM + q * 8;
            #pragma unroll
            for (int ks = 0; ks < 4; ks++) {
                short8 a;
                if (isf32) {
                    const float* xf = (const float*)x + xrow + ks * 32;
                    #pragma unroll
                    for (int i = 0; i < 8; i++) a[i] = (short)f2bfbits(xf[i]);
                } else {
                    a = *(const short8*)((const unsigned short*)x + xrow + ks * 32);
                }
                acc = __builtin_amdgcn_mfma_f32_16x16x32_bf16(a, wb[ks * 64 + lane], acc, 0, 0, 0);
                if (isf32)
                    acc = __builtin_amdgcn_mfma_f32_16x16x32_bf16(a, wbl[ks * 64 + lane], acc, 0, 0, 0);
            }
        }
        #pragma unroll 6
        for (int ksi = 0; ksi < 18; ksi++) {
            int ks = 4 + ksi;
            short8 ah  = *(const short8*)&Ahs[(ksi * 64 + lane) * 8];
            short8 al8 = *(const short8*)&Als[(ksi * 64 + lane) * 8];
            short8 bh = wb[ks * 64 + lane];
            acc = __builtin_amdgcn_mfma_f32_16x16x32_bf16(ah, bh, acc, 0, 0, 0);
            acc = __builtin_amdgcn_mfma_f32_16x16x32_bf16(al8, bh, acc, 0, 0, 0);
            if (isf32)
                acc = __builtin_amdgcn_mfma_f32_16x16x32_bf16(ah, wbl[ks * 64 + lane], acc, 0, 0, 0);
        }
        {
            int n = lane & 15, m0 = (lane >> 4) * 4;
            #pragma unroll
            for (int r = 0; r < 4; r++) scr[wv][m0 + r][n] = acc[r];
        }
        __syncthreads();
        // cell epilogue: thread = (row r, local-u ul); c in one VGPR; h-frag -> AfPn
        {
            int r = tid >> 4, ul = tid & 15;
            float4 g = *(const float4*)&scr[ul >> 2][r][(ul & 3) * 4];
            float4 bb = *(const float4*)&bcS[ul * 4];
            float c2 = sigmoidf_(g.y + bb.y) * cc + sigmoidf_(g.x + bb.x) * tanhf(g.z + bb.z);
            float h2 = sigmoidf_(g.w + bb.w) * tanhf(c2);
            cc = c2;
            hl[r][ul] = h2;
            int u_g = ns * 16 + ul;
            unsigned short hb = f2bfbits(h2);
            unsigned short lb = f2bfbits(h2 - bfbits2f(hb));
            int ksi2 = 2 + (u_g >> 5), q = (u_g & 31) >> 3, e = u_g & 7;
            size_t fi = (((size_t)ms * 18 + ksi2) * 64 + q * 16 + r) * 8 + e;
            astore(AfPn + fi, (unsigned)hb | ((unsigned)lb << 16));
        }
        __syncthreads();
        // readout partials: 16 rows x 13 j per thread-set vs LDS Wr-slice
        {
            int jset = tid >> 4, r2 = tid & 15;
            int row = ms * 16 + r2;
            unsigned* pb = (unsigned*)part + (((size_t)row * 32) + ns) * 208 + jset * 13;
            #pragma unroll
            for (int i = 0; i < 13; i++) {
                int j = jset * 13 + i;
                float p = 0.f;
                #pragma unroll
                for (int k = 0; k < 16; k++) p += bfbits2f(wrsl[j * 16 + k]) * hl[r2][k];
                if (isf32) {
                    #pragma unroll
                    for (int k = 0; k < 16; k++) p += bfbits2f(wrslL[j * 16 + k]) * hl[r2][k];
                }
                astore(pb + i, __builtin_bit_cast(unsigned, p));
            }
        }
        flag_barrier(flags, 2 * t + 1);

        // ---- P2: row-blocks only ----
        if (blk < 128) {
            const int brow = blk;
            if (tid < 208) {
                float s4 = brS[tid];
                const unsigned* pb = (const unsigned*)part + ((size_t)brow * 32) * 208 + tid;
                #pragma unroll 8
                for (int nsI = 0; nsI < 32; nsI++)
                    s4 += __builtin_bit_cast(float, aload(pb + (size_t)nsI * 208));
                outs[tid] = s4;
            }
            __syncthreads();
            if (wv == 0) {
                float uval = sigmoidf_(outs[192]);
                float dval = sigmoidf_(outs[193]);
                Vrow[t * SDIM + lane] = f2bfbits(outs[lane]);
                int ebase = lane * 5;
                float sv[5], suf[5];
                #pragma unroll
                for (int j = 0; j < 5; j++) {
                    int e = ebase + j;
                    sv[j] = (e < MAXT) ? sL[e] : 0.f;
                }
                suf[4] = sv[4];
                #pragma unroll
                for (int j = 3; j >= 0; j--) suf[j] = sv[j] + suf[j + 1];
                float ltot = suf[0];
                float accs = ltot;
                #pragma unroll
                for (int off = 1; off < 64; off <<= 1) {
                    float y = __shfl_down(accs, off, 64);
                    if (lane + off < 64) accs += y;
                }
                float after_lane = accs - ltot;
                #pragma unroll
                for (int j = 0; j < 5; j++) {
                    int e = ebase + j;
                    if (e < MAXT) {
                        float prod = after_lane + (suf[j] - sv[j]);
                        float sp = (e == t) ? dval
                                            : fmaxf(0.f, sv[j] - fmaxf(0.f, uval - prod));
                        float inner = fmaxf(0.f, 1.f - prod - sp);
                        sL[e] = sp;
                        aL[e] = fminf(sp, inner);
                    }
                }
            }
            __syncthreads();
            {
                float racc = 0.f;
                for (int i2 = wv; i2 <= t; i2 += 4)
                    racc += aL[i2] * bfbits2f(Vrow[i2 * SDIM + lane]);
                red[wv][lane] = racc;
            }
            __syncthreads();
            if (wv == 0) {
                float rtv = red[0][lane] + red[1][lane] + red[2][lane] + red[3][lane];
                unsigned short hb = f2bfbits(rtv);
                unsigned short lb = f2bfbits(rtv - bfbits2f(hb));
                int mtB = brow >> 4;
                size_t fi = (((size_t)mtB * 18 + (lane >> 5)) * 64
                             + ((lane & 31) >> 3) * 16 + (brow & 15)) * 8 + (lane & 7);
                astore(AfPn + fi, (unsigned)hb | ((unsigned)lb << 16));
            } else if (wv == 1 && t >= 129) {
                float a = outs[64 + lane];
                float bvv = outs[128 + lane];
                float m = fmaxf(a, bvv);
                #pragma unroll
                for (int off = 32; off; off >>= 1) m = fmaxf(m, __shfl_xor(m, off, 64));
                float e = expf(a - m) + expf(bvv - m);
                #pragma unroll
                for (int off = 32; off; off >>= 1) e += __shfl_xor(e, off, 64);
                float ls = logf(e) + m;
                size_t base = ((size_t)(t - 129) * BATCH + brow) * IDIM;
                if (isf32) {
                    ((float*)dout)[base + lane] = a - ls;
                    ((float*)dout)[base + lane + 64] = bvv - ls;
                } else {
                    ((bf16*)dout)[base + lane] = __float2bfloat16(a - ls);
                    ((bf16*)dout)[base + lane + 64] = __float2bfloat16(bvv - ls);
                }
            }
        }
        flag_barrier(flags, 2 * t + 2);
    }
}

extern "C" void kernel_launch(void* const* d_in, const int* in_sizes, int n_in,
                              void* d_out, int out_size, void* d_ws, size_t ws_size,
                              hipStream_t stream) {
    const void* x   = d_in[0];
    const void* Wih = d_in[1];
    const void* bih = d_in[2];
    const void* Whh = d_in[3];
    const void* bhh = d_in[4];
    const void* Wr  = d_in[5];
    const void* br  = d_in[6];

    char* base = (char*)d_ws;
    size_t off = 0;
    int* flag = (int*)base;                                   off += 64;
    unsigned* flags = (unsigned*)(base + off);                off += 256 * 64 + 64;
    unsigned short* WfH  = (unsigned short*)(base + off);     off += (size_t)G4 * KTOT * 2;
    unsigned short* WfL  = (unsigned short*)(base + off);     off += (size_t)G4 * KTOT * 2;
    unsigned short* WrBh = (unsigned short*)(base + off);     off += (size_t)208 * HDIM * 2;
    unsigned short* WrBl = (unsigned short*)(base + off);     off += (size_t)208 * HDIM * 2;
    float* bc   = (float*)(base + off);                       off += G4 * 4;
    float* brf  = (float*)(base + off);                       off += 1024;
    unsigned* AfP = (unsigned*)(base + off);                  size_t af_off = off;
                                                              off += (size_t)2 * AFRAG_U * 4;
    float* part = (float*)(base + off);                       off += (size_t)BATCH * 32 * 208 * 4;
    unsigned short* Vg = (unsigned short*)(base + off);       off += (size_t)BATCH * MAXT * SDIM * 2;
    // total ~14.5 MB

    hipMemsetAsync(base + 64, 0, 256 * 64 + 64, stream);               // barrier flags
    hipMemsetAsync(base + af_off, 0, (size_t)2 * AFRAG_U * 4, stream); // A-frag buffers

    detect_kernel<<<1, 64, 0, stream>>>((const unsigned short*)Wih, flag);
    prep_kernel<<<G4, 256, 0, stream>>>(Wih, bih, Whh, bhh, WfH, WfL, bc, flag);
    wr_prep_kernel<<<208, 256, 0, stream>>>(Wr, br, WrBh, WrBl, brf, flag);

    persist_kernel<<<NBLK, 256, 0, stream>>>(x, WfH, WfL, bc, WrBh, WrBl, brf,
                                             AfP, part, Vg, d_out, flag, flags);

    (void)in_sizes; (void)n_in; (void)out_size; (void)ws_size;
}